// Round 12
// baseline (482.635 us; speedup 1.0000x reference)
//
#include <hip/hip_runtime.h>
#include <hip/hip_bf16.h>

#define NB 2
#define NS 512
#define NH 32
#define ND 128
#define NT 2048
#define NDM 4096
#define NE 12288

typedef __attribute__((ext_vector_type(4))) float f32x4;
typedef __attribute__((ext_vector_type(8))) short s16x8;
typedef unsigned int u32;

__device__ __forceinline__ short f2bs(float x) {
  unsigned int u = __float_as_uint(x);
  u += 0x7fffu + ((u >> 16) & 1u);
  return (short)(u >> 16);
}
__device__ __forceinline__ float bs2f(short s) {
  return __uint_as_float(((unsigned int)(unsigned short)s) << 16);
}
__device__ __forceinline__ s16x8 cvt8(float4 a, float4 b) {
  s16x8 o;
  o[0] = f2bs(a.x); o[1] = f2bs(a.y); o[2] = f2bs(a.z); o[3] = f2bs(a.w);
  o[4] = f2bs(b.x); o[5] = f2bs(b.y); o[6] = f2bs(b.z); o[7] = f2bs(b.w);
  return o;
}
__device__ __forceinline__ void gl16(const short* g, short* l) {
  __builtin_amdgcn_global_load_lds(
      (const __attribute__((address_space(1))) u32*)g,
      (__attribute__((address_space(3))) u32*)l, 16, 0, 0);
}

// ---------------------------------------------------------------------------
// f32 -> bf16 elementwise (fallback path only).
// ---------------------------------------------------------------------------
__global__ void f2b_kernel(const float* __restrict__ src, short* __restrict__ dst) {
  const size_t i = ((size_t)blockIdx.x * 256 + threadIdx.x) * 8;
  const float4* s = (const float4*)(src + i);
  *(s16x8*)(dst + i) = cvt8(s[0], s[1]);
}

// ---------------------------------------------------------------------------
// Merged prep: one launch, branch per block range (all BW-bound, independent).
//   [0,     2048)  f2b x      -> xb   (24 MB)
//   [2048, 26624)  f2b wqkv   -> wb   (300 MB)
//   [26624,34816)  copyk kc   -> Kf   (100 MB)
//   [34816,38912)  vtrans vc  -> VT   (100 MB + LDS transpose)
// ---------------------------------------------------------------------------
__global__ __launch_bounds__(256) void prep_kernel(
    const float* __restrict__ x, const float* __restrict__ wqkv,
    const float* __restrict__ kc, const float* __restrict__ vc,
    short* __restrict__ xb, short* __restrict__ wb,
    short* __restrict__ Kf, short* __restrict__ VT)
{
  __shared__ float tile[64][69];
  const int bid = blockIdx.x;
  const int tid = threadIdx.x;

  if (bid < 26624) {
    const float* src; short* dst; size_t base;
    if (bid < 2048) { src = x;    dst = xb; base = (size_t)bid * 256; }
    else            { src = wqkv; dst = wb; base = (size_t)(bid - 2048) * 256; }
    const size_t i = (base + tid) * 8;
    const float4* s = (const float4*)(src + i);
    *(s16x8*)(dst + i) = cvt8(s[0], s[1]);
  } else if (bid < 34816) {
    const size_t i = ((size_t)(bid - 26624) * 256 + tid) * 8;
    const float4* s = (const float4*)(kc + i);
    *(s16x8*)(Kf + i) = cvt8(s[0], s[1]);
  } else {
    const int id = bid - 34816;              // 4096 tiles: 64 bh x 2 dd x 32 tt
    const size_t bh = id >> 6;
    const int rem = id & 63;
    const int dd = (rem >> 5) * 64;
    const int tt = (rem & 31) * 64;
    const int row = tid >> 2, c0 = (tid & 3) * 16;
    const float* src = vc + (bh * NT + tt + row) * ND + dd + c0;
    #pragma unroll
    for (int j = 0; j < 4; ++j)
      *(float4*)&tile[row][c0 + j * 4] = *(const float4*)(src + j * 4);
    __syncthreads();
    short tmp[16];
    #pragma unroll
    for (int i = 0; i < 16; ++i) tmp[i] = f2bs(tile[c0 + i][row]);
    short* dst = VT + (bh * ND + dd + row) * NT + tt + c0;
    *(s16x8*)dst       = *(s16x8*)&tmp[0];
    *(s16x8*)(dst + 8) = *(s16x8*)&tmp[8];
  }
}

// ---------------------------------------------------------------------------
// 8-phase bf16 NT GEMM, BM=128 x BN=384, 256 blocks — R7/R10 16x16x32 variant
// (measured-clean: 0 bank conflicts, ~147 us; declared practical ceiling).
// ---------------------------------------------------------------------------
__global__ __launch_bounds__(512, 2) void gemm8p(
    const short* __restrict__ A, const short* __restrict__ B,
    short* __restrict__ C, int M, int N, int K)
{
  __shared__ short ldsA[4 * 4096];    // 4 slots x (128 rows x 32 k)
  __shared__ short ldsB[4 * 12288];   // 4 slots x (384 rows x 32 k)

  const int tid = threadIdx.x;
  const int l   = tid & 63;
  const int w   = tid >> 6;
  const int wm  = w >> 2, wn = w & 3;          // 2 x 4 wave grid
  const int m0  = blockIdx.y * 128, n0 = blockIdx.x * 384;
  const int nhalf = (K / 32) * 2;

  auto STAGE = [&](int s) {
    const int op    = s & 1;
    const int sigma = s >> 1;
    const int slot  = sigma & 3;
    const int k0    = sigma * 32;
    if (op == 0) {
      short* region = ldsA + slot * 4096;
      const int o    = tid * 16;
      const int line = o >> 7;
      const int off  = (o & 127) ^ ((line & 7) << 4);
      const int r    = (line << 1) | (off >> 6);
      const int cb   = off & 63;
      gl16(A + (size_t)(m0 + r) * K + k0 + (cb >> 1), region + (o >> 1));
    } else {
      short* region = ldsB + slot * 12288;
      #pragma unroll
      for (int c = 0; c < 3; ++c) {
        const int o    = c * 8192 + tid * 16;
        const int line = o >> 7;
        const int off  = (o & 127) ^ ((line & 7) << 4);
        const int r    = (line << 1) | (off >> 6);
        const int cb   = off & 63;
        gl16(B + (size_t)(n0 + r) * K + k0 + (cb >> 1), region + (o >> 1));
      }
    }
  };

  const int fcb = (l >> 4) << 4;
  auto FRAGA = [&](int slot, int r) -> s16x8 {
    const int line = r >> 1;
    const int off  = (((r & 1) << 6) | fcb) ^ ((line & 7) << 4);
    return *(const s16x8*)((const char*)(ldsA + slot * 4096) + (line << 7) + off);
  };
  auto FRAGB = [&](int slot, int r) -> s16x8 {
    const int line = r >> 1;
    const int off  = (((r & 1) << 6) | fcb) ^ ((line & 7) << 4);
    return *(const s16x8*)((const char*)(ldsB + slot * 12288) + (line << 7) + off);
  };

  f32x4 acc[4][6] = {};

  for (int s = 0; s < 6; ++s) STAGE(s);
  asm volatile("s_waitcnt vmcnt(4)" ::: "memory");
  __builtin_amdgcn_s_barrier();

  const int ktiles = K / 64;
  for (int j = 0; j < ktiles; ++j) {
    s16x8 bfr[6];
    #pragma unroll
    for (int q = 0; q < 4; ++q) {
      const int kk = q >> 1, mh = q & 1;
      const int slot = (2 * j + kk) & 3;
      s16x8 af[2];
      #pragma unroll
      for (int i = 0; i < 2; ++i)
        af[i] = FRAGA(slot, wm * 64 + (mh * 2 + i) * 16 + (l & 15));
      if (mh == 0) {
        #pragma unroll
        for (int i = 0; i < 6; ++i)
          bfr[i] = FRAGB(slot, wn * 96 + i * 16 + (l & 15));
      }
      const int s = 4 * j + q + 6;
      if (s < nhalf) STAGE(s);
      __builtin_amdgcn_s_barrier();
      __builtin_amdgcn_s_setprio(1);
      #pragma unroll
      for (int i = 0; i < 2; ++i)
        #pragma unroll
        for (int nf = 0; nf < 6; ++nf)
          acc[mh * 2 + i][nf] = __builtin_amdgcn_mfma_f32_16x16x32_bf16(
              af[i], bfr[nf], acc[mh * 2 + i][nf], 0, 0, 0);
      __builtin_amdgcn_s_setprio(0);
      if (q == 3) {
        if (j < ktiles - 2)       asm volatile("s_waitcnt vmcnt(4)" ::: "memory");
        else if (j == ktiles - 2) asm volatile("s_waitcnt vmcnt(0)" ::: "memory");
      }
      __builtin_amdgcn_s_barrier();
    }
  }

  #pragma unroll
  for (int mf = 0; mf < 4; ++mf) {
    const int r0 = m0 + wm * 64 + mf * 16 + (l >> 4) * 4;
    #pragma unroll
    for (int nf = 0; nf < 6; ++nf) {
      const int cc = n0 + wn * 96 + nf * 16 + (l & 15);
      #pragma unroll
      for (int jj = 0; jj < 4; ++jj)
        C[(size_t)(r0 + jj) * N + cc] = f2bs(acc[mf][nf][jj]);
    }
  }
}

// ---------------------------------------------------------------------------
// m97-structure bf16 NT GEMM (out-proj) — unchanged.
// ---------------------------------------------------------------------------
template<bool C_BF16>
__global__ __launch_bounds__(256) void gemm_bt(
    const short* __restrict__ A, const short* __restrict__ B,
    void* __restrict__ Cp, int M, int N, int K)
{
  __shared__ short As[128 * 32];
  __shared__ short Bs[128 * 32];

  const int tid  = threadIdx.x;
  const int lane = tid & 63;
  const int w    = tid >> 6;
  const int wm = (w >> 1) * 64, wn = (w & 1) * 64;
  const int m0 = blockIdx.y * 128, n0 = blockIdx.x * 128;
  const int lr = lane & 15, lko = (lane >> 4) * 8;
  const int srow = lane >> 2, scol = (lane & 3) * 8;

  const short* ga = A + (size_t)(m0 + w * 32 + srow) * K + scol;
  const short* gb = B + (size_t)(n0 + w * 32 + srow) * K + scol;
  short* la = &As[(w * 32 + srow) * 32 + scol];
  short* lb = &Bs[(w * 32 + srow) * 32 + scol];
  const size_t rstep = (size_t)16 * K;

  f32x4 acc[4][4] = {};
  const int ktiles = K / 32;
  for (int kt = 0; kt < ktiles; ++kt) {
    const int ko = kt * 32;
    gl16(ga + ko,         la);
    gl16(ga + rstep + ko, la + 16 * 32);
    gl16(gb + ko,         lb);
    gl16(gb + rstep + ko, lb + 16 * 32);
    __syncthreads();

    s16x8 af[4], bf[4];
    #pragma unroll
    for (int i = 0; i < 4; ++i) {
      af[i] = *(const s16x8*)&As[(wm + i * 16 + lr) * 32 + lko];
      bf[i] = *(const s16x8*)&Bs[(wn + i * 16 + lr) * 32 + lko];
    }
    #pragma unroll
    for (int mi = 0; mi < 4; ++mi)
      #pragma unroll
      for (int ni = 0; ni < 4; ++ni)
        acc[mi][ni] = __builtin_amdgcn_mfma_f32_16x16x32_bf16(
            af[mi], bf[ni], acc[mi][ni], 0, 0, 0);
    __syncthreads();
  }

  #pragma unroll
  for (int mi = 0; mi < 4; ++mi) {
    const int r0 = m0 + wm + mi * 16 + (lane >> 4) * 4;
    #pragma unroll
    for (int ni = 0; ni < 4; ++ni) {
      const int c = n0 + wn + ni * 16 + lr;
      const f32x4 v = acc[mi][ni];
      #pragma unroll
      for (int j = 0; j < 4; ++j) {
        if constexpr (C_BF16)
          ((short*)Cp)[(size_t)(r0 + j) * N + c] = f2bs(v[j]);
        else
          ((float*)Cp)[(size_t)(r0 + j) * N + c] = v[j];
      }
    }
  }
}

// ---------------------------------------------------------------------------
// Fallback GEMM (validated R1 path): f32 operands converted in-flight.
// ---------------------------------------------------------------------------
template<bool A_BF16, bool C_BF16>
__global__ __launch_bounds__(256, 2) void gemm_nt(
    const void* __restrict__ Ap, const float* __restrict__ Bp,
    void* __restrict__ Cp, int M, int N, int K)
{
  constexpr int LP = 40;
  __shared__ short As[2][128][LP];
  __shared__ short Bs[2][128][LP];

  const int tid  = threadIdx.x;
  const int lane = tid & 63;
  const int wv   = tid >> 6;
  const int wm   = (wv >> 1) * 64, wn = (wv & 1) * 64;
  const int m0   = blockIdx.y * 128, n0 = blockIdx.x * 128;
  const int srow = tid >> 1, scol = (tid & 1) * 16;
  const int lr   = lane & 15, lko = (lane >> 4) * 8;

  const float* Af = (const float*)Ap;
  const short* Ab = (const short*)Ap;
  const size_t aOff = (size_t)(m0 + srow) * K + scol;
  const size_t bOff = (size_t)(n0 + srow) * K + scol;

  f32x4 acc[4][4] = {};

  if constexpr (A_BF16) {
    const s16x8* s = (const s16x8*)(Ab + aOff);
    *(s16x8*)&As[0][srow][scol]     = s[0];
    *(s16x8*)&As[0][srow][scol + 8] = s[1];
  } else {
    const float4* s = (const float4*)(Af + aOff);
    *(s16x8*)&As[0][srow][scol]     = cvt8(s[0], s[1]);
    *(s16x8*)&As[0][srow][scol + 8] = cvt8(s[2], s[3]);
  }
  {
    const float4* s = (const float4*)(Bp + bOff);
    *(s16x8*)&Bs[0][srow][scol]     = cvt8(s[0], s[1]);
    *(s16x8*)&Bs[0][srow][scol + 8] = cvt8(s[2], s[3]);
  }
  __syncthreads();

  const int ktiles = K / 32;
  for (int kt = 0; kt < ktiles; ++kt) {
    const int cur = kt & 1;
    const bool has = (kt + 1) < ktiles;
    float4 pa0, pa1, pa2, pa3, pb0, pb1, pb2, pb3;
    s16x8 qa0, qa1;
    if (has) {
      const int k1 = (kt + 1) * 32;
      if constexpr (A_BF16) {
        const s16x8* s = (const s16x8*)(Ab + aOff + k1);
        qa0 = s[0]; qa1 = s[1];
      } else {
        const float4* s = (const float4*)(Af + aOff + k1);
        pa0 = s[0]; pa1 = s[1]; pa2 = s[2]; pa3 = s[3];
      }
      const float4* s = (const float4*)(Bp + bOff + k1);
      pb0 = s[0]; pb1 = s[1]; pb2 = s[2]; pb3 = s[3];
    }
    s16x8 af[4], bf[4];
    #pragma unroll
    for (int i = 0; i < 4; ++i) {
      af[i] = *(const s16x8*)&As[cur][wm + i * 16 + lr][lko];
      bf[i] = *(const s16x8*)&Bs[cur][wn + i * 16 + lr][lko];
    }
    #pragma unroll
    for (int mi = 0; mi < 4; ++mi)
      #pragma unroll
      for (int ni = 0; ni < 4; ++ni)
        acc[mi][ni] = __builtin_amdgcn_mfma_f32_16x16x32_bf16(
            af[mi], bf[ni], acc[mi][ni], 0, 0, 0);
    if (has) {
      const int nxt = cur ^ 1;
      if constexpr (A_BF16) {
        *(s16x8*)&As[nxt][srow][scol]     = qa0;
        *(s16x8*)&As[nxt][srow][scol + 8] = qa1;
      } else {
        *(s16x8*)&As[nxt][srow][scol]     = cvt8(pa0, pa1);
        *(s16x8*)&As[nxt][srow][scol + 8] = cvt8(pa2, pa3);
      }
      *(s16x8*)&Bs[nxt][srow][scol]     = cvt8(pb0, pb1);
      *(s16x8*)&Bs[nxt][srow][scol + 8] = cvt8(pb2, pb3);
    }
    __syncthreads();
  }

  #pragma unroll
  for (int mi = 0; mi < 4; ++mi) {
    const int r0 = m0 + wm + mi * 16 + (lane >> 4) * 4;
    #pragma unroll
    for (int ni = 0; ni < 4; ++ni) {
      const int c = n0 + wn + ni * 16 + lr;
      const f32x4 v = acc[mi][ni];
      #pragma unroll
      for (int j = 0; j < 4; ++j) {
        if constexpr (C_BF16)
          ((short*)Cp)[(size_t)(r0 + j) * N + c] = f2bs(v[j]);
        else
          ((float*)Cp)[(size_t)(r0 + j) * N + c] = v[j];
      }
    }
  }
}

// ---------------------------------------------------------------------------
// k_cache f32 -> bf16 copy (fallback path only).
// ---------------------------------------------------------------------------
__global__ void copyk_kernel(const float* __restrict__ src, short* __restrict__ dst) {
  const size_t i = ((size_t)blockIdx.x * 256 + threadIdx.x) * 8;
  const float4* s = (const float4*)(src + i);
  *(s16x8*)(dst + i) = cvt8(s[0], s[1]);
}

// ---------------------------------------------------------------------------
// v_cache transpose (fallback path only).
// ---------------------------------------------------------------------------
__global__ __launch_bounds__(256) void vtrans_kernel(
    const float* __restrict__ vc, short* __restrict__ VT)
{
  __shared__ float tile[64][69];
  const int tid = threadIdx.x;
  const size_t bh = blockIdx.z;
  const int tt = blockIdx.x * 64;
  const int dd = blockIdx.y * 64;
  const int row = tid >> 2, c0 = (tid & 3) * 16;
  const float* src = vc + (bh * NT + tt + row) * ND + dd + c0;
  #pragma unroll
  for (int j = 0; j < 4; ++j)
    *(float4*)&tile[row][c0 + j * 4] = *(const float4*)(src + j * 4);
  __syncthreads();
  short tmp[16];
  #pragma unroll
  for (int i = 0; i < 16; ++i) tmp[i] = f2bs(tile[c0 + i][row]);
  short* dst = VT + (bh * ND + dd + row) * NT + tt + c0;
  *(s16x8*)dst       = *(s16x8*)&tmp[0];
  *(s16x8*)(dst + 8) = *(s16x8*)&tmp[8];
}

// ---------------------------------------------------------------------------
// RoPE body (shared by rope_wo_kernel fast path and rope_kernel fallback).
// ---------------------------------------------------------------------------
__device__ __forceinline__ void rope_body(
    const short* __restrict__ qkv, const int* __restrict__ ipos,
    const int* __restrict__ bidx, short* __restrict__ Qr,
    short* __restrict__ Kf, short* __restrict__ VT,
    int bs, int tid)
{
  const int b = bs >> 9, s = bs & 511;
  const int h = tid >> 3, r = tid & 7;
  const int pos = ipos[bs];
  const int bi = bidx[b];
  const short* base = qkv + (size_t)bs * NE + h * ND + r * 16;
  const s16x8 q0 = *(const s16x8*)(base);
  const s16x8 q1 = *(const s16x8*)(base + 8);
  const s16x8 k0 = *(const s16x8*)(base + NDM);
  const s16x8 k1 = *(const s16x8*)(base + NDM + 8);
  const s16x8 v0 = *(const s16x8*)(base + 2 * NDM);
  const s16x8 v1 = *(const s16x8*)(base + 2 * NDM + 8);
  const float scale = 0.08838834764831845f;  // 1/sqrt(128)
  s16x8 qo0, qo1, ko0, ko1;
  #pragma unroll
  for (int i = 0; i < 8; ++i) {
    const int d2 = r * 8 + i;
    const float invf = expf(-0.14391156831f * (float)d2);  // 10000^(-d2/64)
    const float ang = (float)pos * invf;
    float sn, cs;
    sincosf(ang, &sn, &cs);
    float x0, x1, y0, y1;
    if (i < 4) {
      x0 = bs2f(q0[2 * i]); x1 = bs2f(q0[2 * i + 1]);
      y0 = bs2f(k0[2 * i]); y1 = bs2f(k0[2 * i + 1]);
    } else {
      x0 = bs2f(q1[2 * i - 8]); x1 = bs2f(q1[2 * i - 7]);
      y0 = bs2f(k1[2 * i - 8]); y1 = bs2f(k1[2 * i - 7]);
    }
    const short oq0 = f2bs((x0 * cs - x1 * sn) * scale);
    const short oq1 = f2bs((x1 * cs + x0 * sn) * scale);
    const short ok0 = f2bs(y0 * cs - y1 * sn);
    const short ok1 = f2bs(y1 * cs + y0 * sn);
    if (i < 4) { qo0[2*i]=oq0; qo0[2*i+1]=oq1; ko0[2*i]=ok0; ko0[2*i+1]=ok1; }
    else       { qo1[2*i-8]=oq0; qo1[2*i-7]=oq1; ko1[2*i-8]=ok0; ko1[2*i-7]=ok1; }
  }
  short* qdst = Qr + (((size_t)b * NH + h) * NS + s) * ND + r * 16;
  *(s16x8*)qdst = qo0; *(s16x8*)(qdst + 8) = qo1;
  short* kdst = Kf + (((size_t)bi * NH + h) * NT + pos) * ND + r * 16;
  *(s16x8*)kdst = ko0; *(s16x8*)(kdst + 8) = ko1;
  short* vdst = VT + (((size_t)bi * NH + h) * ND + r * 16) * NT + pos;
  #pragma unroll
  for (int i = 0; i < 16; ++i) {
    const short vv = (i < 8) ? v0[i] : v1[i - 8];
    vdst[(size_t)i * NT] = vv;
  }
}

// ---------------------------------------------------------------------------
// RoPE + scatter, with f2b(wo) folded in as extra blocks (fast path).
// blocks [0,1024) = rope; [1024, 9216) = wo f32->bf16 into wb
// (wb's wqkv contents are dead after gemm8p).
// ---------------------------------------------------------------------------
__global__ __launch_bounds__(256) void rope_wo_kernel(
    const short* __restrict__ qkv, const int* __restrict__ ipos,
    const int* __restrict__ bidx, short* __restrict__ Qr,
    short* __restrict__ Kf, short* __restrict__ VT,
    const float* __restrict__ wo, short* __restrict__ wb)
{
  if (blockIdx.x >= NB * NS) {
    const size_t i = ((size_t)(blockIdx.x - NB * NS) * 256 + threadIdx.x) * 8;
    const float4* s = (const float4*)(wo + i);
    *(s16x8*)(wb + i) = cvt8(s[0], s[1]);
    return;
  }
  rope_body(qkv, ipos, bidx, Qr, Kf, VT, blockIdx.x, threadIdx.x);
}

// ---------------------------------------------------------------------------
// Standalone rope (fallback path only).
// ---------------------------------------------------------------------------
__global__ __launch_bounds__(256) void rope_kernel(
    const short* __restrict__ qkv, const int* __restrict__ ipos,
    const int* __restrict__ bidx, short* __restrict__ Qr,
    short* __restrict__ Kf, short* __restrict__ VT)
{
  rope_body(qkv, ipos, bidx, Qr, Kf, VT, blockIdx.x, threadIdx.x);
}

// ---------------------------------------------------------------------------
// Flash attention, QB=64 (4 waves x 16 rows), KVB=64, K/V staged (R7 barriers)
// + wave-uniform fulltile causal fast path.
// ---------------------------------------------------------------------------
__global__ __launch_bounds__(256, 2) void attn_kernel(
    const short* __restrict__ Q, const short* __restrict__ Kf,
    const short* __restrict__ VT, const int* __restrict__ ipos,
    short* __restrict__ Y)
{
  __shared__ short Ks[64][136];
  __shared__ short Vs[128][72];
  __shared__ short Ps[64][72];
  __shared__ int pos_sh[64];
  __shared__ int maxpos_sh;

  const int tid = threadIdx.x;
  const int lane = tid & 63;
  const int w = tid >> 6;
  const int s0 = blockIdx.x * 64;
  const int h = blockIdx.y;
  const int b = blockIdx.z;
  const int lr = lane & 15, lg = lane >> 4, lko = lg * 8;

  if (tid < 64) pos_sh[tid] = ipos[b * NS + s0 + tid];
  __syncthreads();
  if (tid == 0) {
    int m = 0;
    for (int i = 0; i < 64; ++i) m = (pos_sh[i] > m) ? pos_sh[i] : m;
    maxpos_sh = m;
  }
  __syncthreads();
  const int maxpos = maxpos_sh;
  const int wmin = pos_sh[w * 16];

  const size_t bh = (size_t)b * NH + h;
  const short* Qp = Q + (bh * NS + s0 + w * 16) * ND;
  s16x8 qf[4];
  #pragma unroll
  for (int kc = 0; kc < 4; ++kc)
    qf[kc] = *(const s16x8*)(Qp + (size_t)lr * ND + kc * 32 + lko);

  int prow[4];
  float mrun[4], lrun[4];
  #pragma unroll
  for (int j = 0; j < 4; ++j) {
    prow[j] = pos_sh[w * 16 + lg * 4 + j];
    mrun[j] = -1e30f;
    lrun[j] = 0.f;
  }
  f32x4 yac[8] = {};

  const short* Kbase = Kf + bh * NT * ND;
  const short* Vbase = VT + bh * ND * NT;
  const int krow = tid >> 2, kc0 = (tid & 3) * 32;
  const int vrow = tid >> 1, vc0 = (tid & 1) * 32;
  const int ntl = maxpos / 64 + 1;

  for (int t = 0; t < ntl; ++t) {
    const int t0 = t * 64;
    {
      const short* src = Kbase + (size_t)(t0 + krow) * ND + kc0;
      #pragma unroll
      for (int j = 0; j < 4; ++j)
        *(s16x8*)&Ks[krow][kc0 + j * 8] = *(const s16x8*)(src + j * 8);
      const short* vsrc = Vbase + (size_t)vrow * NT + t0 + vc0;
      #pragma unroll
      for (int j = 0; j < 4; ++j)
        *(s16x8*)&Vs[vrow][vc0 + j * 8] = *(const s16x8*)(vsrc + j * 8);
    }
    __syncthreads();

    f32x4 sac[4] = {};
    #pragma unroll
    for (int kc = 0; kc < 4; ++kc) {
      s16x8 kfr[4];
      #pragma unroll
      for (int ni = 0; ni < 4; ++ni)
        kfr[ni] = *(const s16x8*)&Ks[ni * 16 + lr][kc * 32 + lko];
      #pragma unroll
      for (int ni = 0; ni < 4; ++ni)
        sac[ni] = __builtin_amdgcn_mfma_f32_16x16x32_bf16(
            qf[kc], kfr[ni], sac[ni], 0, 0, 0);
    }

    const bool fulltile = (t0 + 63) <= wmin;
    float alpha[4];
    #pragma unroll
    for (int j = 0; j < 4; ++j) {
      float mv = -1e30f;
      if (fulltile) {
        #pragma unroll
        for (int ni = 0; ni < 4; ++ni) mv = fmaxf(mv, sac[ni][j]);
      } else {
        const int rp = prow[j];
        #pragma unroll
        for (int ni = 0; ni < 4; ++ni) {
          float sv = sac[ni][j];
          if (t0 + ni * 16 + lr > rp) sv = -1e30f;
          sac[ni][j] = sv;
          mv = fmaxf(mv, sv);
        }
      }
      #pragma unroll
      for (int off = 1; off < 16; off <<= 1)
        mv = fmaxf(mv, __shfl_xor(mv, off, 64));
      const float mo = mrun[j];
      const float mn = fmaxf(mo, mv);
      const float a = __expf(mo - mn);
      mrun[j] = mn;
      float rs = 0.f;
      #pragma unroll
      for (int ni = 0; ni < 4; ++ni) {
        const float p = __expf(sac[ni][j] - mn);
        sac[ni][j] = p;
        rs += p;
      }
      #pragma unroll
      for (int off = 1; off < 16; off <<= 1)
        rs += __shfl_xor(rs, off, 64);
      lrun[j] = lrun[j] * a + rs;
      alpha[j] = a;
    }
    #pragma unroll
    for (int nn = 0; nn < 8; ++nn)
      #pragma unroll
      for (int j = 0; j < 4; ++j)
        yac[nn][j] *= alpha[j];
    #pragma unroll
    for (int ni = 0; ni < 4; ++ni)
      #pragma unroll
      for (int j = 0; j < 4; ++j)
        Ps[w * 16 + lg * 4 + j][ni * 16 + lr] = f2bs(sac[ni][j]);
    __syncthreads();

    #pragma unroll
    for (int kc = 0; kc < 2; ++kc) {
      s16x8 vf[8];
      #pragma unroll
      for (int nn = 0; nn < 8; ++nn)
        vf[nn] = *(const s16x8*)&Vs[nn * 16 + lr][kc * 32 + lko];
      const s16x8 pf = *(const s16x8*)&Ps[w * 16 + lr][kc * 32 + lko];
      #pragma unroll
      for (int nn = 0; nn < 8; ++nn)
        yac[nn] = __builtin_amdgcn_mfma_f32_16x16x32_bf16(
            pf, vf[nn], yac[nn], 0, 0, 0);
    }
    __syncthreads();
  }

  #pragma unroll
  for (int j = 0; j < 4; ++j) {
    const float inv = 1.0f / lrun[j];
    const int srow = s0 + w * 16 + lg * 4 + j;
    short* yp = Y + ((size_t)b * NS + srow) * NDM + h * ND;
    #pragma unroll
    for (int nn = 0; nn < 8; ++nn)
      yp[nn * 16 + lr] = f2bs(yac[nn][j] * inv);
  }
}

// ---------------------------------------------------------------------------
extern "C" void kernel_launch(void* const* d_in, const int* in_sizes, int n_in,
                              void* d_out, int out_size, void* d_ws, size_t ws_size,
                              hipStream_t stream)
{
  (void)in_sizes; (void)n_in; (void)out_size;
  const float* x    = (const float*)d_in[0];
  const float* wqkv = (const float*)d_in[1];
  const float* wo   = (const float*)d_in[2];
  const float* kc   = (const float*)d_in[3];
  const float* vc   = (const float*)d_in[4];
  const int*   bidx = (const int*)d_in[5];
  const int*   ipos = (const int*)d_in[6];
  float* out = (float*)d_out;

  // workspace layout:
  //   [0,          25165824)  qkv bf16 [B,S,3*DM]   (later aliased by Y)
  //   [25165824,   33554432)  Qr  bf16 [B,H,S,D]    (xb aliases this pre-rope)
  //   [33554432,   67108864)  Kf  bf16 [B,H,T,D]
  //   [67108864,  100663296)  VT  bf16 [B,H,D,T]
  //   [100663296, 201326592)  wb  bf16 (wqkv for gemm1, then wo for gemm2)
  char* ws = (char*)d_ws;
  short* qkv = (short*)(ws);
  short* Qr  = (short*)(ws + 25165824ull);
  short* Kf  = (short*)(ws + 33554432ull);
  short* VT  = (short*)(ws + 67108864ull);
  short* Y   = qkv;            // alias: qkv dead after rope
  short* xb  = Qr;             // alias: xb dead before rope writes Qr
  short* wb  = (short*)(ws + 100663296ull);

  const size_t WS_NEEDED = 201326592ull;

  if (ws_size >= WS_NEEDED) {
    // fast path: 5 dispatches (merged prep; rope+wo-convert merged)
    prep_kernel<<<dim3(38912), 256, 0, stream>>>(x, wqkv, kc, vc, xb, wb, Kf, VT);
    gemm8p<<<dim3(NE / 384, (NB * NS) / 128), 512, 0, stream>>>(
        xb, wb, qkv, NB * NS, NE, NDM);
    rope_wo_kernel<<<dim3(NB * NS + 8192), 256, 0, stream>>>(
        qkv, ipos, bidx, Qr, Kf, VT, wo, wb);
    attn_kernel<<<dim3(NS / 64, NH, NB), 256, 0, stream>>>(Qr, Kf, VT, ipos, Y);
    gemm_bt<false><<<dim3(NDM / 128, (NB * NS) / 128), 256, 0, stream>>>(
        Y, wb, out, NB * NS, NDM, NDM);
  } else {
    // fallback: validated R1 path (fused f32 conversion GEMM), 96 MiB ws
    gemm_nt<false, true><<<dim3(NE / 128, (NB * NS) / 128), 256, 0, stream>>>(
        x, wqkv, qkv, NB * NS, NE, NDM);
    copyk_kernel<<<dim3(8192), 256, 0, stream>>>(kc, Kf);
    vtrans_kernel<<<dim3(NT / 64, ND / 64, NB * NH), 256, 0, stream>>>(vc, VT);
    rope_kernel<<<dim3(NB * NS), 256, 0, stream>>>(qkv, ipos, bidx, Qr, Kf, VT);
    attn_kernel<<<dim3(NS / 64, NH, NB), 256, 0, stream>>>(Qr, Kf, VT, ipos, Y);
    gemm_nt<true, false><<<dim3(NDM / 128, (NB * NS) / 128), 256, 0, stream>>>(
        Y, wo, out, NB * NS, NDM, NDM);
  }
}

// Round 13
// 454.606 us; speedup vs baseline: 1.0617x; 1.0617x over previous
//
#include <hip/hip_runtime.h>
#include <hip/hip_bf16.h>

#define NB 2
#define NS 512
#define NH 32
#define ND 128
#define NT 2048
#define NDM 4096
#define NE 12288

typedef __attribute__((ext_vector_type(4))) float f32x4;
typedef __attribute__((ext_vector_type(8))) short s16x8;
typedef unsigned int u32;

__device__ __forceinline__ short f2bs(float x) {
  unsigned int u = __float_as_uint(x);
  u += 0x7fffu + ((u >> 16) & 1u);
  return (short)(u >> 16);
}
__device__ __forceinline__ float bs2f(short s) {
  return __uint_as_float(((unsigned int)(unsigned short)s) << 16);
}
__device__ __forceinline__ s16x8 cvt8(float4 a, float4 b) {
  s16x8 o;
  o[0] = f2bs(a.x); o[1] = f2bs(a.y); o[2] = f2bs(a.z); o[3] = f2bs(a.w);
  o[4] = f2bs(b.x); o[5] = f2bs(b.y); o[6] = f2bs(b.z); o[7] = f2bs(b.w);
  return o;
}
__device__ __forceinline__ void gl16(const short* g, short* l) {
  __builtin_amdgcn_global_load_lds(
      (const __attribute__((address_space(1))) u32*)g,
      (__attribute__((address_space(3))) u32*)l, 16, 0, 0);
}

// ---------------------------------------------------------------------------
// f32 -> bf16 elementwise, 8 elems/thread.
// ---------------------------------------------------------------------------
__global__ void f2b_kernel(const float* __restrict__ src, short* __restrict__ dst) {
  const size_t i = ((size_t)blockIdx.x * 256 + threadIdx.x) * 8;
  const float4* s = (const float4*)(src + i);
  *(s16x8*)(dst + i) = cvt8(s[0], s[1]);
}

// ---------------------------------------------------------------------------
// 8-phase bf16 NT GEMM, BM=128 x BN=384, 256 blocks — 16x16x32 variant
// (measured-clean: 0 bank conflicts, 146-149 us in R10).
// ---------------------------------------------------------------------------
__global__ __launch_bounds__(512, 2) void gemm8p(
    const short* __restrict__ A, const short* __restrict__ B,
    short* __restrict__ C, int M, int N, int K)
{
  __shared__ short ldsA[4 * 4096];    // 4 slots x (128 rows x 32 k)
  __shared__ short ldsB[4 * 12288];   // 4 slots x (384 rows x 32 k)

  const int tid = threadIdx.x;
  const int l   = tid & 63;
  const int w   = tid >> 6;
  const int wm  = w >> 2, wn = w & 3;          // 2 x 4 wave grid
  const int m0  = blockIdx.y * 128, n0 = blockIdx.x * 384;
  const int nhalf = (K / 32) * 2;

  auto STAGE = [&](int s) {
    const int op    = s & 1;
    const int sigma = s >> 1;
    const int slot  = sigma & 3;
    const int k0    = sigma * 32;
    if (op == 0) {
      short* region = ldsA + slot * 4096;
      const int o    = tid * 16;
      const int line = o >> 7;
      const int off  = (o & 127) ^ ((line & 7) << 4);
      const int r    = (line << 1) | (off >> 6);
      const int cb   = off & 63;
      gl16(A + (size_t)(m0 + r) * K + k0 + (cb >> 1), region + (o >> 1));
    } else {
      short* region = ldsB + slot * 12288;
      #pragma unroll
      for (int c = 0; c < 3; ++c) {
        const int o    = c * 8192 + tid * 16;
        const int line = o >> 7;
        const int off  = (o & 127) ^ ((line & 7) << 4);
        const int r    = (line << 1) | (off >> 6);
        const int cb   = off & 63;
        gl16(B + (size_t)(n0 + r) * K + k0 + (cb >> 1), region + (o >> 1));
      }
    }
  };

  const int fcb = (l >> 4) << 4;
  auto FRAGA = [&](int slot, int r) -> s16x8 {
    const int line = r >> 1;
    const int off  = (((r & 1) << 6) | fcb) ^ ((line & 7) << 4);
    return *(const s16x8*)((const char*)(ldsA + slot * 4096) + (line << 7) + off);
  };
  auto FRAGB = [&](int slot, int r) -> s16x8 {
    const int line = r >> 1;
    const int off  = (((r & 1) << 6) | fcb) ^ ((line & 7) << 4);
    return *(const s16x8*)((const char*)(ldsB + slot * 12288) + (line << 7) + off);
  };

  f32x4 acc[4][6] = {};

  for (int s = 0; s < 6; ++s) STAGE(s);
  asm volatile("s_waitcnt vmcnt(4)" ::: "memory");
  __builtin_amdgcn_s_barrier();

  const int ktiles = K / 64;
  for (int j = 0; j < ktiles; ++j) {
    s16x8 bfr[6];
    #pragma unroll
    for (int q = 0; q < 4; ++q) {
      const int kk = q >> 1, mh = q & 1;
      const int slot = (2 * j + kk) & 3;
      s16x8 af[2];
      #pragma unroll
      for (int i = 0; i < 2; ++i)
        af[i] = FRAGA(slot, wm * 64 + (mh * 2 + i) * 16 + (l & 15));
      if (mh == 0) {
        #pragma unroll
        for (int i = 0; i < 6; ++i)
          bfr[i] = FRAGB(slot, wn * 96 + i * 16 + (l & 15));
      }
      const int s = 4 * j + q + 6;
      if (s < nhalf) STAGE(s);
      __builtin_amdgcn_s_barrier();
      __builtin_amdgcn_s_setprio(1);
      #pragma unroll
      for (int i = 0; i < 2; ++i)
        #pragma unroll
        for (int nf = 0; nf < 6; ++nf)
          acc[mh * 2 + i][nf] = __builtin_amdgcn_mfma_f32_16x16x32_bf16(
              af[i], bfr[nf], acc[mh * 2 + i][nf], 0, 0, 0);
      __builtin_amdgcn_s_setprio(0);
      if (q == 3) {
        if (j < ktiles - 2)       asm volatile("s_waitcnt vmcnt(4)" ::: "memory");
        else if (j == ktiles - 2) asm volatile("s_waitcnt vmcnt(0)" ::: "memory");
      }
      __builtin_amdgcn_s_barrier();
    }
  }

  #pragma unroll
  for (int mf = 0; mf < 4; ++mf) {
    const int r0 = m0 + wm * 64 + mf * 16 + (l >> 4) * 4;
    #pragma unroll
    for (int nf = 0; nf < 6; ++nf) {
      const int cc = n0 + wn * 96 + nf * 16 + (l & 15);
      #pragma unroll
      for (int jj = 0; jj < 4; ++jj)
        C[(size_t)(r0 + jj) * N + cc] = f2bs(acc[mf][nf][jj]);
    }
  }
}

// ---------------------------------------------------------------------------
// m97-structure bf16 NT GEMM (out-proj) — unchanged.
// ---------------------------------------------------------------------------
template<bool C_BF16>
__global__ __launch_bounds__(256) void gemm_bt(
    const short* __restrict__ A, const short* __restrict__ B,
    void* __restrict__ Cp, int M, int N, int K)
{
  __shared__ short As[128 * 32];
  __shared__ short Bs[128 * 32];

  const int tid  = threadIdx.x;
  const int lane = tid & 63;
  const int w    = tid >> 6;
  const int wm = (w >> 1) * 64, wn = (w & 1) * 64;
  const int m0 = blockIdx.y * 128, n0 = blockIdx.x * 128;
  const int lr = lane & 15, lko = (lane >> 4) * 8;
  const int srow = lane >> 2, scol = (lane & 3) * 8;

  const short* ga = A + (size_t)(m0 + w * 32 + srow) * K + scol;
  const short* gb = B + (size_t)(n0 + w * 32 + srow) * K + scol;
  short* la = &As[(w * 32 + srow) * 32 + scol];
  short* lb = &Bs[(w * 32 + srow) * 32 + scol];
  const size_t rstep = (size_t)16 * K;

  f32x4 acc[4][4] = {};
  const int ktiles = K / 32;
  for (int kt = 0; kt < ktiles; ++kt) {
    const int ko = kt * 32;
    gl16(ga + ko,         la);
    gl16(ga + rstep + ko, la + 16 * 32);
    gl16(gb + ko,         lb);
    gl16(gb + rstep + ko, lb + 16 * 32);
    __syncthreads();

    s16x8 af[4], bf[4];
    #pragma unroll
    for (int i = 0; i < 4; ++i) {
      af[i] = *(const s16x8*)&As[(wm + i * 16 + lr) * 32 + lko];
      bf[i] = *(const s16x8*)&Bs[(wn + i * 16 + lr) * 32 + lko];
    }
    #pragma unroll
    for (int mi = 0; mi < 4; ++mi)
      #pragma unroll
      for (int ni = 0; ni < 4; ++ni)
        acc[mi][ni] = __builtin_amdgcn_mfma_f32_16x16x32_bf16(
            af[mi], bf[ni], acc[mi][ni], 0, 0, 0);
    __syncthreads();
  }

  #pragma unroll
  for (int mi = 0; mi < 4; ++mi) {
    const int r0 = m0 + wm + mi * 16 + (lane >> 4) * 4;
    #pragma unroll
    for (int ni = 0; ni < 4; ++ni) {
      const int c = n0 + wn + ni * 16 + lr;
      const f32x4 v = acc[mi][ni];
      #pragma unroll
      for (int j = 0; j < 4; ++j) {
        if constexpr (C_BF16)
          ((short*)Cp)[(size_t)(r0 + j) * N + c] = f2bs(v[j]);
        else
          ((float*)Cp)[(size_t)(r0 + j) * N + c] = v[j];
      }
    }
  }
}

// ---------------------------------------------------------------------------
// Fallback GEMM (validated R1 path): f32 operands converted in-flight.
// ---------------------------------------------------------------------------
template<bool A_BF16, bool C_BF16>
__global__ __launch_bounds__(256, 2) void gemm_nt(
    const void* __restrict__ Ap, const float* __restrict__ Bp,
    void* __restrict__ Cp, int M, int N, int K)
{
  constexpr int LP = 40;
  __shared__ short As[2][128][LP];
  __shared__ short Bs[2][128][LP];

  const int tid  = threadIdx.x;
  const int lane = tid & 63;
  const int wv   = tid >> 6;
  const int wm   = (wv >> 1) * 64, wn = (wv & 1) * 64;
  const int m0   = blockIdx.y * 128, n0 = blockIdx.x * 128;
  const int srow = tid >> 1, scol = (tid & 1) * 16;
  const int lr   = lane & 15, lko = (lane >> 4) * 8;

  const float* Af = (const float*)Ap;
  const short* Ab = (const short*)Ap;
  const size_t aOff = (size_t)(m0 + srow) * K + scol;
  const size_t bOff = (size_t)(n0 + srow) * K + scol;

  f32x4 acc[4][4] = {};

  if constexpr (A_BF16) {
    const s16x8* s = (const s16x8*)(Ab + aOff);
    *(s16x8*)&As[0][srow][scol]     = s[0];
    *(s16x8*)&As[0][srow][scol + 8] = s[1];
  } else {
    const float4* s = (const float4*)(Af + aOff);
    *(s16x8*)&As[0][srow][scol]     = cvt8(s[0], s[1]);
    *(s16x8*)&As[0][srow][scol + 8] = cvt8(s[2], s[3]);
  }
  {
    const float4* s = (const float4*)(Bp + bOff);
    *(s16x8*)&Bs[0][srow][scol]     = cvt8(s[0], s[1]);
    *(s16x8*)&Bs[0][srow][scol + 8] = cvt8(s[2], s[3]);
  }
  __syncthreads();

  const int ktiles = K / 32;
  for (int kt = 0; kt < ktiles; ++kt) {
    const int cur = kt & 1;
    const bool has = (kt + 1) < ktiles;
    float4 pa0, pa1, pa2, pa3, pb0, pb1, pb2, pb3;
    s16x8 qa0, qa1;
    if (has) {
      const int k1 = (kt + 1) * 32;
      if constexpr (A_BF16) {
        const s16x8* s = (const s16x8*)(Ab + aOff + k1);
        qa0 = s[0]; qa1 = s[1];
      } else {
        const float4* s = (const float4*)(Af + aOff + k1);
        pa0 = s[0]; pa1 = s[1]; pa2 = s[2]; pa3 = s[3];
      }
      const float4* s = (const float4*)(Bp + bOff + k1);
      pb0 = s[0]; pb1 = s[1]; pb2 = s[2]; pb3 = s[3];
    }
    s16x8 af[4], bf[4];
    #pragma unroll
    for (int i = 0; i < 4; ++i) {
      af[i] = *(const s16x8*)&As[cur][wm + i * 16 + lr][lko];
      bf[i] = *(const s16x8*)&Bs[cur][wn + i * 16 + lr][lko];
    }
    #pragma unroll
    for (int mi = 0; mi < 4; ++mi)
      #pragma unroll
      for (int ni = 0; ni < 4; ++ni)
        acc[mi][ni] = __builtin_amdgcn_mfma_f32_16x16x32_bf16(
            af[mi], bf[ni], acc[mi][ni], 0, 0, 0);
    if (has) {
      const int nxt = cur ^ 1;
      if constexpr (A_BF16) {
        *(s16x8*)&As[nxt][srow][scol]     = qa0;
        *(s16x8*)&As[nxt][srow][scol + 8] = qa1;
      } else {
        *(s16x8*)&As[nxt][srow][scol]     = cvt8(pa0, pa1);
        *(s16x8*)&As[nxt][srow][scol + 8] = cvt8(pa2, pa3);
      }
      *(s16x8*)&Bs[nxt][srow][scol]     = cvt8(pb0, pb1);
      *(s16x8*)&Bs[nxt][srow][scol + 8] = cvt8(pb2, pb3);
    }
    __syncthreads();
  }

  #pragma unroll
  for (int mi = 0; mi < 4; ++mi) {
    const int r0 = m0 + wm + mi * 16 + (lane >> 4) * 4;
    #pragma unroll
    for (int ni = 0; ni < 4; ++ni) {
      const int c = n0 + wn + ni * 16 + lr;
      const f32x4 v = acc[mi][ni];
      #pragma unroll
      for (int j = 0; j < 4; ++j) {
        if constexpr (C_BF16)
          ((short*)Cp)[(size_t)(r0 + j) * N + c] = f2bs(v[j]);
        else
          ((float*)Cp)[(size_t)(r0 + j) * N + c] = v[j];
      }
    }
  }
}

// ---------------------------------------------------------------------------
// k_cache f32 [B,H,T,D] -> K_full bf16 (same layout). 8 elems/thread.
// ---------------------------------------------------------------------------
__global__ void copyk_kernel(const float* __restrict__ src, short* __restrict__ dst) {
  const size_t i = ((size_t)blockIdx.x * 256 + threadIdx.x) * 8;
  const float4* s = (const float4*)(src + i);
  *(s16x8*)(dst + i) = cvt8(s[0], s[1]);
}

// ---------------------------------------------------------------------------
// v_cache f32 [B,H,T,D] -> VT bf16 [B,H,D,T] via 64x64 LDS tile transpose.
// Stride 69 (odd): col-major read conflict 4-way -> free 2-way.
// ---------------------------------------------------------------------------
__global__ __launch_bounds__(256) void vtrans_kernel(
    const float* __restrict__ vc, short* __restrict__ VT)
{
  __shared__ float tile[64][69];
  const int tid = threadIdx.x;
  const size_t bh = blockIdx.z;
  const int tt = blockIdx.x * 64;
  const int dd = blockIdx.y * 64;
  const int row = tid >> 2, c0 = (tid & 3) * 16;
  const float* src = vc + (bh * NT + tt + row) * ND + dd + c0;
  #pragma unroll
  for (int j = 0; j < 4; ++j)
    *(float4*)&tile[row][c0 + j * 4] = *(const float4*)(src + j * 4);
  __syncthreads();
  short tmp[16];
  #pragma unroll
  for (int i = 0; i < 16; ++i) tmp[i] = f2bs(tile[c0 + i][row]);
  short* dst = VT + (bh * ND + dd + row) * NT + tt + c0;
  *(s16x8*)dst       = *(s16x8*)&tmp[0];
  *(s16x8*)(dst + 8) = *(s16x8*)&tmp[8];
}

// ---------------------------------------------------------------------------
// RoPE q,k (fold 1/sqrt(D) into q) + scatter k/v into K_full / VT at pos.
// ---------------------------------------------------------------------------
__global__ __launch_bounds__(256) void rope_kernel(
    const short* __restrict__ qkv, const int* __restrict__ ipos,
    const int* __restrict__ bidx, short* __restrict__ Qr,
    short* __restrict__ Kf, short* __restrict__ VT)
{
  const int bs = blockIdx.x;
  const int b = bs >> 9, s = bs & 511;
  const int tid = threadIdx.x;
  const int h = tid >> 3, r = tid & 7;
  const int pos = ipos[bs];
  const int bi = bidx[b];
  const short* base = qkv + (size_t)bs * NE + h * ND + r * 16;
  const s16x8 q0 = *(const s16x8*)(base);
  const s16x8 q1 = *(const s16x8*)(base + 8);
  const s16x8 k0 = *(const s16x8*)(base + NDM);
  const s16x8 k1 = *(const s16x8*)(base + NDM + 8);
  const s16x8 v0 = *(const s16x8*)(base + 2 * NDM);
  const s16x8 v1 = *(const s16x8*)(base + 2 * NDM + 8);
  const float scale = 0.08838834764831845f;  // 1/sqrt(128)
  s16x8 qo0, qo1, ko0, ko1;
  #pragma unroll
  for (int i = 0; i < 8; ++i) {
    const int d2 = r * 8 + i;
    const float invf = expf(-0.14391156831f * (float)d2);  // 10000^(-d2/64)
    const float ang = (float)pos * invf;
    float sn, cs;
    sincosf(ang, &sn, &cs);
    float x0, x1, y0, y1;
    if (i < 4) {
      x0 = bs2f(q0[2 * i]); x1 = bs2f(q0[2 * i + 1]);
      y0 = bs2f(k0[2 * i]); y1 = bs2f(k0[2 * i + 1]);
    } else {
      x0 = bs2f(q1[2 * i - 8]); x1 = bs2f(q1[2 * i - 7]);
      y0 = bs2f(k1[2 * i - 8]); y1 = bs2f(k1[2 * i - 7]);
    }
    const short oq0 = f2bs((x0 * cs - x1 * sn) * scale);
    const short oq1 = f2bs((x1 * cs + x0 * sn) * scale);
    const short ok0 = f2bs(y0 * cs - y1 * sn);
    const short ok1 = f2bs(y1 * cs + y0 * sn);
    if (i < 4) { qo0[2*i]=oq0; qo0[2*i+1]=oq1; ko0[2*i]=ok0; ko0[2*i+1]=ok1; }
    else       { qo1[2*i-8]=oq0; qo1[2*i-7]=oq1; ko1[2*i-8]=ok0; ko1[2*i-7]=ok1; }
  }
  short* qdst = Qr + (((size_t)b * NH + h) * NS + s) * ND + r * 16;
  *(s16x8*)qdst = qo0; *(s16x8*)(qdst + 8) = qo1;
  short* kdst = Kf + (((size_t)bi * NH + h) * NT + pos) * ND + r * 16;
  *(s16x8*)kdst = ko0; *(s16x8*)(kdst + 8) = ko1;
  short* vdst = VT + (((size_t)bi * NH + h) * ND + r * 16) * NT + pos;
  #pragma unroll
  for (int i = 0; i < 16; ++i) {
    const short vv = (i < 8) ? v0[i] : v1[i - 8];
    vdst[(size_t)i * NT] = vv;
  }
}

// ---------------------------------------------------------------------------
// Flash attention, QB=64 (4 waves x 16 rows), KVB=64 — exact R7/R8 structure
// (3 barriers/tile, always-masked; the version in both best-measured runs).
// ---------------------------------------------------------------------------
__global__ __launch_bounds__(256, 2) void attn_kernel(
    const short* __restrict__ Q, const short* __restrict__ Kf,
    const short* __restrict__ VT, const int* __restrict__ ipos,
    short* __restrict__ Y)
{
  __shared__ short Ks[64][136];
  __shared__ short Vs[128][72];
  __shared__ short Ps[64][72];
  __shared__ int pos_sh[64];
  __shared__ int maxpos_sh;

  const int tid = threadIdx.x;
  const int lane = tid & 63;
  const int w = tid >> 6;
  const int s0 = blockIdx.x * 64;
  const int h = blockIdx.y;
  const int b = blockIdx.z;
  const int lr = lane & 15, lg = lane >> 4, lko = lg * 8;

  if (tid < 64) pos_sh[tid] = ipos[b * NS + s0 + tid];
  __syncthreads();
  if (tid == 0) {
    int m = 0;
    for (int i = 0; i < 64; ++i) m = (pos_sh[i] > m) ? pos_sh[i] : m;
    maxpos_sh = m;
  }
  __syncthreads();
  const int maxpos = maxpos_sh;

  const size_t bh = (size_t)b * NH + h;
  const short* Qp = Q + (bh * NS + s0 + w * 16) * ND;
  s16x8 qf[4];
  #pragma unroll
  for (int kc = 0; kc < 4; ++kc)
    qf[kc] = *(const s16x8*)(Qp + (size_t)lr * ND + kc * 32 + lko);

  int prow[4];
  float mrun[4], lrun[4];
  #pragma unroll
  for (int j = 0; j < 4; ++j) {
    prow[j] = pos_sh[w * 16 + lg * 4 + j];
    mrun[j] = -1e30f;
    lrun[j] = 0.f;
  }
  f32x4 yac[8] = {};

  const short* Kbase = Kf + bh * NT * ND;
  const short* Vbase = VT + bh * ND * NT;
  const int krow = tid >> 2, kc0 = (tid & 3) * 32;
  const int vrow = tid >> 1, vc0 = (tid & 1) * 32;
  const int ntl = maxpos / 64 + 1;

  for (int t = 0; t < ntl; ++t) {
    const int t0 = t * 64;
    {
      const short* src = Kbase + (size_t)(t0 + krow) * ND + kc0;
      #pragma unroll
      for (int j = 0; j < 4; ++j)
        *(s16x8*)&Ks[krow][kc0 + j * 8] = *(const s16x8*)(src + j * 8);
      const short* vsrc = Vbase + (size_t)vrow * NT + t0 + vc0;
      #pragma unroll
      for (int j = 0; j < 4; ++j)
        *(s16x8*)&Vs[vrow][vc0 + j * 8] = *(const s16x8*)(vsrc + j * 8);
    }
    __syncthreads();

    f32x4 sac[4] = {};
    #pragma unroll
    for (int kc = 0; kc < 4; ++kc) {
      s16x8 kfr[4];
      #pragma unroll
      for (int ni = 0; ni < 4; ++ni)
        kfr[ni] = *(const s16x8*)&Ks[ni * 16 + lr][kc * 32 + lko];
      #pragma unroll
      for (int ni = 0; ni < 4; ++ni)
        sac[ni] = __builtin_amdgcn_mfma_f32_16x16x32_bf16(
            qf[kc], kfr[ni], sac[ni], 0, 0, 0);
    }

    float alpha[4];
    #pragma unroll
    for (int j = 0; j < 4; ++j) {
      const int rp = prow[j];
      float mv = -1e30f;
      #pragma unroll
      for (int ni = 0; ni < 4; ++ni) {
        float sv = sac[ni][j];
        if (t0 + ni * 16 + lr > rp) sv = -1e30f;
        sac[ni][j] = sv;
        mv = fmaxf(mv, sv);
      }
      #pragma unroll
      for (int off = 1; off < 16; off <<= 1)
        mv = fmaxf(mv, __shfl_xor(mv, off, 64));
      const float mo = mrun[j];
      const float mn = fmaxf(mo, mv);
      const float a = __expf(mo - mn);
      mrun[j] = mn;
      float rs = 0.f;
      #pragma unroll
      for (int ni = 0; ni < 4; ++ni) {
        const float p = __expf(sac[ni][j] - mn);
        sac[ni][j] = p;
        rs += p;
      }
      #pragma unroll
      for (int off = 1; off < 16; off <<= 1)
        rs += __shfl_xor(rs, off, 64);
      lrun[j] = lrun[j] * a + rs;
      alpha[j] = a;
    }
    #pragma unroll
    for (int nn = 0; nn < 8; ++nn)
      #pragma unroll
      for (int j = 0; j < 4; ++j)
        yac[nn][j] *= alpha[j];
    #pragma unroll
    for (int ni = 0; ni < 4; ++ni)
      #pragma unroll
      for (int j = 0; j < 4; ++j)
        Ps[w * 16 + lg * 4 + j][ni * 16 + lr] = f2bs(sac[ni][j]);
    __syncthreads();

    #pragma unroll
    for (int kc = 0; kc < 2; ++kc) {
      s16x8 vf[8];
      #pragma unroll
      for (int nn = 0; nn < 8; ++nn)
        vf[nn] = *(const s16x8*)&Vs[nn * 16 + lr][kc * 32 + lko];
      const s16x8 pf = *(const s16x8*)&Ps[w * 16 + lr][kc * 32 + lko];
      #pragma unroll
      for (int nn = 0; nn < 8; ++nn)
        yac[nn] = __builtin_amdgcn_mfma_f32_16x16x32_bf16(
            pf, vf[nn], yac[nn], 0, 0, 0);
    }
    __syncthreads();
  }

  #pragma unroll
  for (int j = 0; j < 4; ++j) {
    const float inv = 1.0f / lrun[j];
    const int srow = s0 + w * 16 + lg * 4 + j;
    short* yp = Y + ((size_t)b * NS + srow) * NDM + h * ND;
    #pragma unroll
    for (int nn = 0; nn < 8; ++nn)
      yp[nn * 16 + lr] = f2bs(yac[nn][j] * inv);
  }
}

// ---------------------------------------------------------------------------
extern "C" void kernel_launch(void* const* d_in, const int* in_sizes, int n_in,
                              void* d_out, int out_size, void* d_ws, size_t ws_size,
                              hipStream_t stream)
{
  (void)in_sizes; (void)n_in; (void)out_size;
  const float* x    = (const float*)d_in[0];
  const float* wqkv = (const float*)d_in[1];
  const float* wo   = (const float*)d_in[2];
  const float* kc   = (const float*)d_in[3];
  const float* vc   = (const float*)d_in[4];
  const int*   bidx = (const int*)d_in[5];
  const int*   ipos = (const int*)d_in[6];
  float* out = (float*)d_out;

  // workspace layout:
  //   [0,          25165824)  qkv bf16 [B,S,3*DM]   (later aliased by Y)
  //   [25165824,   33554432)  Qr  bf16 [B,H,S,D]    (xb aliases this pre-rope)
  //   [33554432,   67108864)  Kf  bf16 [B,H,T,D]
  //   [67108864,  100663296)  VT  bf16 [B,H,D,T]
  //   [100663296, 201326592)  wb  bf16 (wqkv for gemm1, then wo for gemm2)
  char* ws = (char*)d_ws;
  short* qkv = (short*)(ws);
  short* Qr  = (short*)(ws + 25165824ull);
  short* Kf  = (short*)(ws + 33554432ull);
  short* VT  = (short*)(ws + 67108864ull);
  short* Y   = qkv;            // alias: qkv dead after rope_kernel
  short* xb  = Qr;             // alias: xb dead before rope writes Qr
  short* wb  = (short*)(ws + 100663296ull);

  const size_t WS_NEEDED = 201326592ull;

  if (ws_size >= WS_NEEDED) {
    // fast path: R8 launch config with 16x16-clean gemm8p
    f2b_kernel<<<dim3(2048),  256, 0, stream>>>(x, xb);
    f2b_kernel<<<dim3(24576), 256, 0, stream>>>(wqkv, wb);
    gemm8p<<<dim3(NE / 384, (NB * NS) / 128), 512, 0, stream>>>(
        xb, wb, qkv, NB * NS, NE, NDM);
    copyk_kernel<<<dim3(8192), 256, 0, stream>>>(kc, Kf);
    vtrans_kernel<<<dim3(NT / 64, ND / 64, NB * NH), 256, 0, stream>>>(vc, VT);
    rope_kernel<<<dim3(NB * NS), 256, 0, stream>>>(qkv, ipos, bidx, Qr, Kf, VT);
    attn_kernel<<<dim3(NS / 64, NH, NB), 256, 0, stream>>>(Qr, Kf, VT, ipos, Y);
    f2b_kernel<<<dim3(8192), 256, 0, stream>>>(wo, wb);
    gemm_bt<false><<<dim3(NDM / 128, (NB * NS) / 128), 256, 0, stream>>>(
        Y, wb, out, NB * NS, NDM, NDM);
  } else {
    // fallback: validated R1 path (fused f32 conversion GEMM), 96 MiB ws
    gemm_nt<false, true><<<dim3(NE / 128, (NB * NS) / 128), 256, 0, stream>>>(
        x, wqkv, qkv, NB * NS, NE, NDM);
    copyk_kernel<<<dim3(8192), 256, 0, stream>>>(kc, Kf);
    vtrans_kernel<<<dim3(NT / 64, ND / 64, NB * NH), 256, 0, stream>>>(vc, VT);
    rope_kernel<<<dim3(NB * NS), 256, 0, stream>>>(qkv, ipos, bidx, Qr, Kf, VT);
    attn_kernel<<<dim3(NS / 64, NH, NB), 256, 0, stream>>>(Qr, Kf, VT, ipos, Y);
    gemm_nt<true, false><<<dim3(NDM / 128, (NB * NS) / 128), 256, 0, stream>>>(
        Y, wo, out, NB * NS, NDM, NDM);
  }
}

// Round 14
// 446.261 us; speedup vs baseline: 1.0815x; 1.0187x over previous
//
#include <hip/hip_runtime.h>
#include <hip/hip_bf16.h>

#define NB 2
#define NS 512
#define NH 32
#define ND 128
#define NT 2048
#define NDM 4096
#define NE 12288

typedef __attribute__((ext_vector_type(4))) float f32x4;
typedef __attribute__((ext_vector_type(8))) short s16x8;
typedef unsigned int u32;

__device__ __forceinline__ short f2bs(float x) {
  unsigned int u = __float_as_uint(x);
  u += 0x7fffu + ((u >> 16) & 1u);
  return (short)(u >> 16);
}
__device__ __forceinline__ float bs2f(short s) {
  return __uint_as_float(((unsigned int)(unsigned short)s) << 16);
}
__device__ __forceinline__ s16x8 cvt8(float4 a, float4 b) {
  s16x8 o;
  o[0] = f2bs(a.x); o[1] = f2bs(a.y); o[2] = f2bs(a.z); o[3] = f2bs(a.w);
  o[4] = f2bs(b.x); o[5] = f2bs(b.y); o[6] = f2bs(b.z); o[7] = f2bs(b.w);
  return o;
}
__device__ __forceinline__ void gl16(const short* g, short* l) {
  __builtin_amdgcn_global_load_lds(
      (const __attribute__((address_space(1))) u32*)g,
      (__attribute__((address_space(3))) u32*)l, 16, 0, 0);
}

// ---------------------------------------------------------------------------
// f32 -> bf16 elementwise, 8 elems/thread.
// ---------------------------------------------------------------------------
__global__ void f2b_kernel(const float* __restrict__ src, short* __restrict__ dst) {
  const size_t i = ((size_t)blockIdx.x * 256 + threadIdx.x) * 8;
  const float4* s = (const float4*)(src + i);
  *(s16x8*)(dst + i) = cvt8(s[0], s[1]);
}

// ---------------------------------------------------------------------------
// 8-phase bf16 NT GEMM, BM=128 x BN=384, 256 blocks — 16x16x32 variant
// (measured-clean: 0 bank conflicts, 146-156 us across R10/R13).
// ---------------------------------------------------------------------------
__global__ __launch_bounds__(512, 2) void gemm8p(
    const short* __restrict__ A, const short* __restrict__ B,
    short* __restrict__ C, int M, int N, int K)
{
  __shared__ short ldsA[4 * 4096];    // 4 slots x (128 rows x 32 k)
  __shared__ short ldsB[4 * 12288];   // 4 slots x (384 rows x 32 k)

  const int tid = threadIdx.x;
  const int l   = tid & 63;
  const int w   = tid >> 6;
  const int wm  = w >> 2, wn = w & 3;          // 2 x 4 wave grid
  const int m0  = blockIdx.y * 128, n0 = blockIdx.x * 384;
  const int nhalf = (K / 32) * 2;

  auto STAGE = [&](int s) {
    const int op    = s & 1;
    const int sigma = s >> 1;
    const int slot  = sigma & 3;
    const int k0    = sigma * 32;
    if (op == 0) {
      short* region = ldsA + slot * 4096;
      const int o    = tid * 16;
      const int line = o >> 7;
      const int off  = (o & 127) ^ ((line & 7) << 4);
      const int r    = (line << 1) | (off >> 6);
      const int cb   = off & 63;
      gl16(A + (size_t)(m0 + r) * K + k0 + (cb >> 1), region + (o >> 1));
    } else {
      short* region = ldsB + slot * 12288;
      #pragma unroll
      for (int c = 0; c < 3; ++c) {
        const int o    = c * 8192 + tid * 16;
        const int line = o >> 7;
        const int off  = (o & 127) ^ ((line & 7) << 4);
        const int r    = (line << 1) | (off >> 6);
        const int cb   = off & 63;
        gl16(B + (size_t)(n0 + r) * K + k0 + (cb >> 1), region + (o >> 1));
      }
    }
  };

  const int fcb = (l >> 4) << 4;
  auto FRAGA = [&](int slot, int r) -> s16x8 {
    const int line = r >> 1;
    const int off  = (((r & 1) << 6) | fcb) ^ ((line & 7) << 4);
    return *(const s16x8*)((const char*)(ldsA + slot * 4096) + (line << 7) + off);
  };
  auto FRAGB = [&](int slot, int r) -> s16x8 {
    const int line = r >> 1;
    const int off  = (((r & 1) << 6) | fcb) ^ ((line & 7) << 4);
    return *(const s16x8*)((const char*)(ldsB + slot * 12288) + (line << 7) + off);
  };

  f32x4 acc[4][6] = {};

  for (int s = 0; s < 6; ++s) STAGE(s);
  asm volatile("s_waitcnt vmcnt(4)" ::: "memory");
  __builtin_amdgcn_s_barrier();

  const int ktiles = K / 64;
  for (int j = 0; j < ktiles; ++j) {
    s16x8 bfr[6];
    #pragma unroll
    for (int q = 0; q < 4; ++q) {
      const int kk = q >> 1, mh = q & 1;
      const int slot = (2 * j + kk) & 3;
      s16x8 af[2];
      #pragma unroll
      for (int i = 0; i < 2; ++i)
        af[i] = FRAGA(slot, wm * 64 + (mh * 2 + i) * 16 + (l & 15));
      if (mh == 0) {
        #pragma unroll
        for (int i = 0; i < 6; ++i)
          bfr[i] = FRAGB(slot, wn * 96 + i * 16 + (l & 15));
      }
      const int s = 4 * j + q + 6;
      if (s < nhalf) STAGE(s);
      __builtin_amdgcn_s_barrier();
      __builtin_amdgcn_s_setprio(1);
      #pragma unroll
      for (int i = 0; i < 2; ++i)
        #pragma unroll
        for (int nf = 0; nf < 6; ++nf)
          acc[mh * 2 + i][nf] = __builtin_amdgcn_mfma_f32_16x16x32_bf16(
              af[i], bfr[nf], acc[mh * 2 + i][nf], 0, 0, 0);
      __builtin_amdgcn_s_setprio(0);
      if (q == 3) {
        if (j < ktiles - 2)       asm volatile("s_waitcnt vmcnt(4)" ::: "memory");
        else if (j == ktiles - 2) asm volatile("s_waitcnt vmcnt(0)" ::: "memory");
      }
      __builtin_amdgcn_s_barrier();
    }
  }

  #pragma unroll
  for (int mf = 0; mf < 4; ++mf) {
    const int r0 = m0 + wm * 64 + mf * 16 + (l >> 4) * 4;
    #pragma unroll
    for (int nf = 0; nf < 6; ++nf) {
      const int cc = n0 + wn * 96 + nf * 16 + (l & 15);
      #pragma unroll
      for (int jj = 0; jj < 4; ++jj)
        C[(size_t)(r0 + jj) * N + cc] = f2bs(acc[mf][nf][jj]);
    }
  }
}

// ---------------------------------------------------------------------------
// m97-structure bf16 NT GEMM (out-proj) — unchanged.
// ---------------------------------------------------------------------------
template<bool C_BF16>
__global__ __launch_bounds__(256) void gemm_bt(
    const short* __restrict__ A, const short* __restrict__ B,
    void* __restrict__ Cp, int M, int N, int K)
{
  __shared__ short As[128 * 32];
  __shared__ short Bs[128 * 32];

  const int tid  = threadIdx.x;
  const int lane = tid & 63;
  const int w    = tid >> 6;
  const int wm = (w >> 1) * 64, wn = (w & 1) * 64;
  const int m0 = blockIdx.y * 128, n0 = blockIdx.x * 128;
  const int lr = lane & 15, lko = (lane >> 4) * 8;
  const int srow = lane >> 2, scol = (lane & 3) * 8;

  const short* ga = A + (size_t)(m0 + w * 32 + srow) * K + scol;
  const short* gb = B + (size_t)(n0 + w * 32 + srow) * K + scol;
  short* la = &As[(w * 32 + srow) * 32 + scol];
  short* lb = &Bs[(w * 32 + srow) * 32 + scol];
  const size_t rstep = (size_t)16 * K;

  f32x4 acc[4][4] = {};
  const int ktiles = K / 32;
  for (int kt = 0; kt < ktiles; ++kt) {
    const int ko = kt * 32;
    gl16(ga + ko,         la);
    gl16(ga + rstep + ko, la + 16 * 32);
    gl16(gb + ko,         lb);
    gl16(gb + rstep + ko, lb + 16 * 32);
    __syncthreads();

    s16x8 af[4], bf[4];
    #pragma unroll
    for (int i = 0; i < 4; ++i) {
      af[i] = *(const s16x8*)&As[(wm + i * 16 + lr) * 32 + lko];
      bf[i] = *(const s16x8*)&Bs[(wn + i * 16 + lr) * 32 + lko];
    }
    #pragma unroll
    for (int mi = 0; mi < 4; ++mi)
      #pragma unroll
      for (int ni = 0; ni < 4; ++ni)
        acc[mi][ni] = __builtin_amdgcn_mfma_f32_16x16x32_bf16(
            af[mi], bf[ni], acc[mi][ni], 0, 0, 0);
    __syncthreads();
  }

  #pragma unroll
  for (int mi = 0; mi < 4; ++mi) {
    const int r0 = m0 + wm + mi * 16 + (lane >> 4) * 4;
    #pragma unroll
    for (int ni = 0; ni < 4; ++ni) {
      const int c = n0 + wn + ni * 16 + lr;
      const f32x4 v = acc[mi][ni];
      #pragma unroll
      for (int j = 0; j < 4; ++j) {
        if constexpr (C_BF16)
          ((short*)Cp)[(size_t)(r0 + j) * N + c] = f2bs(v[j]);
        else
          ((float*)Cp)[(size_t)(r0 + j) * N + c] = v[j];
      }
    }
  }
}

// ---------------------------------------------------------------------------
// Fallback GEMM (validated R1 path): f32 operands converted in-flight.
// ---------------------------------------------------------------------------
template<bool A_BF16, bool C_BF16>
__global__ __launch_bounds__(256, 2) void gemm_nt(
    const void* __restrict__ Ap, const float* __restrict__ Bp,
    void* __restrict__ Cp, int M, int N, int K)
{
  constexpr int LP = 40;
  __shared__ short As[2][128][LP];
  __shared__ short Bs[2][128][LP];

  const int tid  = threadIdx.x;
  const int lane = tid & 63;
  const int wv   = tid >> 6;
  const int wm   = (wv >> 1) * 64, wn = (wv & 1) * 64;
  const int m0   = blockIdx.y * 128, n0 = blockIdx.x * 128;
  const int srow = tid >> 1, scol = (tid & 1) * 16;
  const int lr   = lane & 15, lko = (lane >> 4) * 8;

  const float* Af = (const float*)Ap;
  const short* Ab = (const short*)Ap;
  const size_t aOff = (size_t)(m0 + srow) * K + scol;
  const size_t bOff = (size_t)(n0 + srow) * K + scol;

  f32x4 acc[4][4] = {};

  if constexpr (A_BF16) {
    const s16x8* s = (const s16x8*)(Ab + aOff);
    *(s16x8*)&As[0][srow][scol]     = s[0];
    *(s16x8*)&As[0][srow][scol + 8] = s[1];
  } else {
    const float4* s = (const float4*)(Af + aOff);
    *(s16x8*)&As[0][srow][scol]     = cvt8(s[0], s[1]);
    *(s16x8*)&As[0][srow][scol + 8] = cvt8(s[2], s[3]);
  }
  {
    const float4* s = (const float4*)(Bp + bOff);
    *(s16x8*)&Bs[0][srow][scol]     = cvt8(s[0], s[1]);
    *(s16x8*)&Bs[0][srow][scol + 8] = cvt8(s[2], s[3]);
  }
  __syncthreads();

  const int ktiles = K / 32;
  for (int kt = 0; kt < ktiles; ++kt) {
    const int cur = kt & 1;
    const bool has = (kt + 1) < ktiles;
    float4 pa0, pa1, pa2, pa3, pb0, pb1, pb2, pb3;
    s16x8 qa0, qa1;
    if (has) {
      const int k1 = (kt + 1) * 32;
      if constexpr (A_BF16) {
        const s16x8* s = (const s16x8*)(Ab + aOff + k1);
        qa0 = s[0]; qa1 = s[1];
      } else {
        const float4* s = (const float4*)(Af + aOff + k1);
        pa0 = s[0]; pa1 = s[1]; pa2 = s[2]; pa3 = s[3];
      }
      const float4* s = (const float4*)(Bp + bOff + k1);
      pb0 = s[0]; pb1 = s[1]; pb2 = s[2]; pb3 = s[3];
    }
    s16x8 af[4], bf[4];
    #pragma unroll
    for (int i = 0; i < 4; ++i) {
      af[i] = *(const s16x8*)&As[cur][wm + i * 16 + lr][lko];
      bf[i] = *(const s16x8*)&Bs[cur][wn + i * 16 + lr][lko];
    }
    #pragma unroll
    for (int mi = 0; mi < 4; ++mi)
      #pragma unroll
      for (int ni = 0; ni < 4; ++ni)
        acc[mi][ni] = __builtin_amdgcn_mfma_f32_16x16x32_bf16(
            af[mi], bf[ni], acc[mi][ni], 0, 0, 0);
    if (has) {
      const int nxt = cur ^ 1;
      if constexpr (A_BF16) {
        *(s16x8*)&As[nxt][srow][scol]     = qa0;
        *(s16x8*)&As[nxt][srow][scol + 8] = qa1;
      } else {
        *(s16x8*)&As[nxt][srow][scol]     = cvt8(pa0, pa1);
        *(s16x8*)&As[nxt][srow][scol + 8] = cvt8(pa2, pa3);
      }
      *(s16x8*)&Bs[nxt][srow][scol]     = cvt8(pb0, pb1);
      *(s16x8*)&Bs[nxt][srow][scol + 8] = cvt8(pb2, pb3);
    }
    __syncthreads();
  }

  #pragma unroll
  for (int mi = 0; mi < 4; ++mi) {
    const int r0 = m0 + wm + mi * 16 + (lane >> 4) * 4;
    #pragma unroll
    for (int ni = 0; ni < 4; ++ni) {
      const int c = n0 + wn + ni * 16 + lr;
      const f32x4 v = acc[mi][ni];
      #pragma unroll
      for (int j = 0; j < 4; ++j) {
        if constexpr (C_BF16)
          ((short*)Cp)[(size_t)(r0 + j) * N + c] = f2bs(v[j]);
        else
          ((float*)Cp)[(size_t)(r0 + j) * N + c] = v[j];
      }
    }
  }
}

// ---------------------------------------------------------------------------
// k_cache f32 [B,H,T,D] -> K_full bf16 (same layout). 8 elems/thread.
// ---------------------------------------------------------------------------
__global__ void copyk_kernel(const float* __restrict__ src, short* __restrict__ dst) {
  const size_t i = ((size_t)blockIdx.x * 256 + threadIdx.x) * 8;
  const float4* s = (const float4*)(src + i);
  *(s16x8*)(dst + i) = cvt8(s[0], s[1]);
}

// ---------------------------------------------------------------------------
// v_cache f32 [B,H,T,D] -> VT bf16 [B,H,D,T] via 64x64 LDS tile transpose.
// Stride 69 (odd): col-major read conflict 4-way -> free 2-way.
// ---------------------------------------------------------------------------
__global__ __launch_bounds__(256) void vtrans_kernel(
    const float* __restrict__ vc, short* __restrict__ VT)
{
  __shared__ float tile[64][69];
  const int tid = threadIdx.x;
  const size_t bh = blockIdx.z;
  const int tt = blockIdx.x * 64;
  const int dd = blockIdx.y * 64;
  const int row = tid >> 2, c0 = (tid & 3) * 16;
  const float* src = vc + (bh * NT + tt + row) * ND + dd + c0;
  #pragma unroll
  for (int j = 0; j < 4; ++j)
    *(float4*)&tile[row][c0 + j * 4] = *(const float4*)(src + j * 4);
  __syncthreads();
  short tmp[16];
  #pragma unroll
  for (int i = 0; i < 16; ++i) tmp[i] = f2bs(tile[c0 + i][row]);
  short* dst = VT + (bh * ND + dd + row) * NT + tt + c0;
  *(s16x8*)dst       = *(s16x8*)&tmp[0];
  *(s16x8*)(dst + 8) = *(s16x8*)&tmp[8];
}

// ---------------------------------------------------------------------------
// RoPE body (shared by rope_wo_kernel fast path and rope_kernel fallback).
// ---------------------------------------------------------------------------
__device__ __forceinline__ void rope_body(
    const short* __restrict__ qkv, const int* __restrict__ ipos,
    const int* __restrict__ bidx, short* __restrict__ Qr,
    short* __restrict__ Kf, short* __restrict__ VT,
    int bs, int tid)
{
  const int b = bs >> 9, s = bs & 511;
  const int h = tid >> 3, r = tid & 7;
  const int pos = ipos[bs];
  const int bi = bidx[b];
  const short* base = qkv + (size_t)bs * NE + h * ND + r * 16;
  const s16x8 q0 = *(const s16x8*)(base);
  const s16x8 q1 = *(const s16x8*)(base + 8);
  const s16x8 k0 = *(const s16x8*)(base + NDM);
  const s16x8 k1 = *(const s16x8*)(base + NDM + 8);
  const s16x8 v0 = *(const s16x8*)(base + 2 * NDM);
  const s16x8 v1 = *(const s16x8*)(base + 2 * NDM + 8);
  const float scale = 0.08838834764831845f;  // 1/sqrt(128)
  s16x8 qo0, qo1, ko0, ko1;
  #pragma unroll
  for (int i = 0; i < 8; ++i) {
    const int d2 = r * 8 + i;
    const float invf = expf(-0.14391156831f * (float)d2);  // 10000^(-d2/64)
    const float ang = (float)pos * invf;
    float sn, cs;
    sincosf(ang, &sn, &cs);
    float x0, x1, y0, y1;
    if (i < 4) {
      x0 = bs2f(q0[2 * i]); x1 = bs2f(q0[2 * i + 1]);
      y0 = bs2f(k0[2 * i]); y1 = bs2f(k0[2 * i + 1]);
    } else {
      x0 = bs2f(q1[2 * i - 8]); x1 = bs2f(q1[2 * i - 7]);
      y0 = bs2f(k1[2 * i - 8]); y1 = bs2f(k1[2 * i - 7]);
    }
    const short oq0 = f2bs((x0 * cs - x1 * sn) * scale);
    const short oq1 = f2bs((x1 * cs + x0 * sn) * scale);
    const short ok0 = f2bs(y0 * cs - y1 * sn);
    const short ok1 = f2bs(y1 * cs + y0 * sn);
    if (i < 4) { qo0[2*i]=oq0; qo0[2*i+1]=oq1; ko0[2*i]=ok0; ko0[2*i+1]=ok1; }
    else       { qo1[2*i-8]=oq0; qo1[2*i-7]=oq1; ko1[2*i-8]=ok0; ko1[2*i-7]=ok1; }
  }
  short* qdst = Qr + (((size_t)b * NH + h) * NS + s) * ND + r * 16;
  *(s16x8*)qdst = qo0; *(s16x8*)(qdst + 8) = qo1;
  short* kdst = Kf + (((size_t)bi * NH + h) * NT + pos) * ND + r * 16;
  *(s16x8*)kdst = ko0; *(s16x8*)(kdst + 8) = ko1;
  short* vdst = VT + (((size_t)bi * NH + h) * ND + r * 16) * NT + pos;
  #pragma unroll
  for (int i = 0; i < 16; ++i) {
    const short vv = (i < 8) ? v0[i] : v1[i - 8];
    vdst[(size_t)i * NT] = vv;
  }
}

// ---------------------------------------------------------------------------
// RoPE + scatter, with f2b(wo) folded in as extra blocks (fast path).
// blocks [0,1024) = rope; [1024, 9216) = wo f32->bf16 into wb
// (wb's wqkv contents are dead after gemm8p). No LDS in either branch,
// so no occupancy coupling (the mechanism that sank R12's prep merge).
// ---------------------------------------------------------------------------
__global__ __launch_bounds__(256) void rope_wo_kernel(
    const short* __restrict__ qkv, const int* __restrict__ ipos,
    const int* __restrict__ bidx, short* __restrict__ Qr,
    short* __restrict__ Kf, short* __restrict__ VT,
    const float* __restrict__ wo, short* __restrict__ wb)
{
  if (blockIdx.x >= NB * NS) {
    const size_t i = ((size_t)(blockIdx.x - NB * NS) * 256 + threadIdx.x) * 8;
    const float4* s = (const float4*)(wo + i);
    *(s16x8*)(wb + i) = cvt8(s[0], s[1]);
    return;
  }
  rope_body(qkv, ipos, bidx, Qr, Kf, VT, blockIdx.x, threadIdx.x);
}

// ---------------------------------------------------------------------------
// Standalone rope (fallback path only).
// ---------------------------------------------------------------------------
__global__ __launch_bounds__(256) void rope_kernel(
    const short* __restrict__ qkv, const int* __restrict__ ipos,
    const int* __restrict__ bidx, short* __restrict__ Qr,
    short* __restrict__ Kf, short* __restrict__ VT)
{
  rope_body(qkv, ipos, bidx, Qr, Kf, VT, blockIdx.x, threadIdx.x);
}

// ---------------------------------------------------------------------------
// Flash attention, QB=64 (4 waves x 16 rows), KVB=64 — exact R7/R8/R13
// structure (3 barriers/tile, always-masked; the version in all best runs).
// ---------------------------------------------------------------------------
__global__ __launch_bounds__(256, 2) void attn_kernel(
    const short* __restrict__ Q, const short* __restrict__ Kf,
    const short* __restrict__ VT, const int* __restrict__ ipos,
    short* __restrict__ Y)
{
  __shared__ short Ks[64][136];
  __shared__ short Vs[128][72];
  __shared__ short Ps[64][72];
  __shared__ int pos_sh[64];
  __shared__ int maxpos_sh;

  const int tid = threadIdx.x;
  const int lane = tid & 63;
  const int w = tid >> 6;
  const int s0 = blockIdx.x * 64;
  const int h = blockIdx.y;
  const int b = blockIdx.z;
  const int lr = lane & 15, lg = lane >> 4, lko = lg * 8;

  if (tid < 64) pos_sh[tid] = ipos[b * NS + s0 + tid];
  __syncthreads();
  if (tid == 0) {
    int m = 0;
    for (int i = 0; i < 64; ++i) m = (pos_sh[i] > m) ? pos_sh[i] : m;
    maxpos_sh = m;
  }
  __syncthreads();
  const int maxpos = maxpos_sh;

  const size_t bh = (size_t)b * NH + h;
  const short* Qp = Q + (bh * NS + s0 + w * 16) * ND;
  s16x8 qf[4];
  #pragma unroll
  for (int kc = 0; kc < 4; ++kc)
    qf[kc] = *(const s16x8*)(Qp + (size_t)lr * ND + kc * 32 + lko);

  int prow[4];
  float mrun[4], lrun[4];
  #pragma unroll
  for (int j = 0; j < 4; ++j) {
    prow[j] = pos_sh[w * 16 + lg * 4 + j];
    mrun[j] = -1e30f;
    lrun[j] = 0.f;
  }
  f32x4 yac[8] = {};

  const short* Kbase = Kf + bh * NT * ND;
  const short* Vbase = VT + bh * ND * NT;
  const int krow = tid >> 2, kc0 = (tid & 3) * 32;
  const int vrow = tid >> 1, vc0 = (tid & 1) * 32;
  const int ntl = maxpos / 64 + 1;

  for (int t = 0; t < ntl; ++t) {
    const int t0 = t * 64;
    {
      const short* src = Kbase + (size_t)(t0 + krow) * ND + kc0;
      #pragma unroll
      for (int j = 0; j < 4; ++j)
        *(s16x8*)&Ks[krow][kc0 + j * 8] = *(const s16x8*)(src + j * 8);
      const short* vsrc = Vbase + (size_t)vrow * NT + t0 + vc0;
      #pragma unroll
      for (int j = 0; j < 4; ++j)
        *(s16x8*)&Vs[vrow][vc0 + j * 8] = *(const s16x8*)(vsrc + j * 8);
    }
    __syncthreads();

    f32x4 sac[4] = {};
    #pragma unroll
    for (int kc = 0; kc < 4; ++kc) {
      s16x8 kfr[4];
      #pragma unroll
      for (int ni = 0; ni < 4; ++ni)
        kfr[ni] = *(const s16x8*)&Ks[ni * 16 + lr][kc * 32 + lko];
      #pragma unroll
      for (int ni = 0; ni < 4; ++ni)
        sac[ni] = __builtin_amdgcn_mfma_f32_16x16x32_bf16(
            qf[kc], kfr[ni], sac[ni], 0, 0, 0);
    }

    float alpha[4];
    #pragma unroll
    for (int j = 0; j < 4; ++j) {
      const int rp = prow[j];
      float mv = -1e30f;
      #pragma unroll
      for (int ni = 0; ni < 4; ++ni) {
        float sv = sac[ni][j];
        if (t0 + ni * 16 + lr > rp) sv = -1e30f;
        sac[ni][j] = sv;
        mv = fmaxf(mv, sv);
      }
      #pragma unroll
      for (int off = 1; off < 16; off <<= 1)
        mv = fmaxf(mv, __shfl_xor(mv, off, 64));
      const float mo = mrun[j];
      const float mn = fmaxf(mo, mv);
      const float a = __expf(mo - mn);
      mrun[j] = mn;
      float rs = 0.f;
      #pragma unroll
      for (int ni = 0; ni < 4; ++ni) {
        const float p = __expf(sac[ni][j] - mn);
        sac[ni][j] = p;
        rs += p;
      }
      #pragma unroll
      for (int off = 1; off < 16; off <<= 1)
        rs += __shfl_xor(rs, off, 64);
      lrun[j] = lrun[j] * a + rs;
      alpha[j] = a;
    }
    #pragma unroll
    for (int nn = 0; nn < 8; ++nn)
      #pragma unroll
      for (int j = 0; j < 4; ++j)
        yac[nn][j] *= alpha[j];
    #pragma unroll
    for (int ni = 0; ni < 4; ++ni)
      #pragma unroll
      for (int j = 0; j < 4; ++j)
        Ps[w * 16 + lg * 4 + j][ni * 16 + lr] = f2bs(sac[ni][j]);
    __syncthreads();

    #pragma unroll
    for (int kc = 0; kc < 2; ++kc) {
      s16x8 vf[8];
      #pragma unroll
      for (int nn = 0; nn < 8; ++nn)
        vf[nn] = *(const s16x8*)&Vs[nn * 16 + lr][kc * 32 + lko];
      const s16x8 pf = *(const s16x8*)&Ps[w * 16 + lr][kc * 32 + lko];
      #pragma unroll
      for (int nn = 0; nn < 8; ++nn)
        yac[nn] = __builtin_amdgcn_mfma_f32_16x16x32_bf16(
            pf, vf[nn], yac[nn], 0, 0, 0);
    }
    __syncthreads();
  }

  #pragma unroll
  for (int j = 0; j < 4; ++j) {
    const float inv = 1.0f / lrun[j];
    const int srow = s0 + w * 16 + lg * 4 + j;
    short* yp = Y + ((size_t)b * NS + srow) * NDM + h * ND;
    #pragma unroll
    for (int nn = 0; nn < 8; ++nn)
      yp[nn * 16 + lr] = f2bs(yac[nn][j] * inv);
  }
}

// ---------------------------------------------------------------------------
extern "C" void kernel_launch(void* const* d_in, const int* in_sizes, int n_in,
                              void* d_out, int out_size, void* d_ws, size_t ws_size,
                              hipStream_t stream)
{
  (void)in_sizes; (void)n_in; (void)out_size;
  const float* x    = (const float*)d_in[0];
  const float* wqkv = (const float*)d_in[1];
  const float* wo   = (const float*)d_in[2];
  const float* kc   = (const float*)d_in[3];
  const float* vc   = (const float*)d_in[4];
  const int*   bidx = (const int*)d_in[5];
  const int*   ipos = (const int*)d_in[6];
  float* out = (float*)d_out;

  // workspace layout:
  //   [0,          25165824)  qkv bf16 [B,S,3*DM]   (later aliased by Y)
  //   [25165824,   33554432)  Qr  bf16 [B,H,S,D]    (xb aliases this pre-rope)
  //   [33554432,   67108864)  Kf  bf16 [B,H,T,D]
  //   [67108864,  100663296)  VT  bf16 [B,H,D,T]
  //   [100663296, 201326592)  wb  bf16 (wqkv for gemm1, then wo for gemm2)
  char* ws = (char*)d_ws;
  short* qkv = (short*)(ws);
  short* Qr  = (short*)(ws + 25165824ull);
  short* Kf  = (short*)(ws + 33554432ull);
  short* VT  = (short*)(ws + 67108864ull);
  short* Y   = qkv;            // alias: qkv dead after rope
  short* xb  = Qr;             // alias: xb dead before rope writes Qr
  short* wb  = (short*)(ws + 100663296ull);

  const size_t WS_NEEDED = 201326592ull;

  if (ws_size >= WS_NEEDED) {
    // fast path: converged R13 config + rope/wo-convert fusion (8 dispatches)
    f2b_kernel<<<dim3(2048),  256, 0, stream>>>(x, xb);
    f2b_kernel<<<dim3(24576), 256, 0, stream>>>(wqkv, wb);
    gemm8p<<<dim3(NE / 384, (NB * NS) / 128), 512, 0, stream>>>(
        xb, wb, qkv, NB * NS, NE, NDM);
    copyk_kernel<<<dim3(8192), 256, 0, stream>>>(kc, Kf);
    vtrans_kernel<<<dim3(NT / 64, ND / 64, NB * NH), 256, 0, stream>>>(vc, VT);
    rope_wo_kernel<<<dim3(NB * NS + 8192), 256, 0, stream>>>(
        qkv, ipos, bidx, Qr, Kf, VT, wo, wb);
    attn_kernel<<<dim3(NS / 64, NH, NB), 256, 0, stream>>>(Qr, Kf, VT, ipos, Y);
    gemm_bt<false><<<dim3(NDM / 128, (NB * NS) / 128), 256, 0, stream>>>(
        Y, wb, out, NB * NS, NDM, NDM);
  } else {
    // fallback: validated R1 path (fused f32 conversion GEMM), 96 MiB ws
    gemm_nt<false, true><<<dim3(NE / 128, (NB * NS) / 128), 256, 0, stream>>>(
        x, wqkv, qkv, NB * NS, NE, NDM);
    copyk_kernel<<<dim3(8192), 256, 0, stream>>>(kc, Kf);
    vtrans_kernel<<<dim3(NT / 64, ND / 64, NB * NH), 256, 0, stream>>>(vc, VT);
    rope_kernel<<<dim3(NB * NS), 256, 0, stream>>>(qkv, ipos, bidx, Qr, Kf, VT);
    attn_kernel<<<dim3(NS / 64, NH, NB), 256, 0, stream>>>(Qr, Kf, VT, ipos, Y);
    gemm_nt<true, false><<<dim3(NDM / 128, (NB * NS) / 128), 256, 0, stream>>>(
        Y, wo, out, NB * NS, NDM, NDM);
  }
}